// Round 1
// baseline (1238.393 us; speedup 1.0000x reference)
//
#include <hip/hip_runtime.h>

typedef float f2 __attribute__((ext_vector_type(2)));
typedef float f4 __attribute__((ext_vector_type(4)));

#define TT 2048
#define BB 512
#define II 10
#define HH 20

// One wave (64 lanes) per (direction, batch-sample) sequence.
// Lane l owns gate g0=l; lanes 0..15 additionally own gate g1=64+l.
// Gate order (PyTorch): i[0:20], f[20:40], g[40:60], o[60:80].
__global__ __launch_bounds__(64) void lstm_bidir(
    const float* __restrict__ x,
    const float* __restrict__ w_ih_f, const float* __restrict__ w_hh_f,
    const float* __restrict__ b_ih_f, const float* __restrict__ b_hh_f,
    const float* __restrict__ w_ih_r, const float* __restrict__ w_hh_r,
    const float* __restrict__ b_ih_r, const float* __restrict__ b_hh_r,
    float* __restrict__ out)
{
    const int lane = threadIdx.x;
    const int blk  = blockIdx.x;
    const int dir  = blk >> 9;     // 0 = forward, 1 = reverse
    const int s    = blk & 511;    // batch sample

    const float* __restrict__ w_ih = dir ? w_ih_r : w_ih_f;
    const float* __restrict__ w_hh = dir ? w_hh_r : w_hh_f;
    const float* __restrict__ b_ih = dir ? b_ih_r : b_ih_f;
    const float* __restrict__ b_hh = dir ? b_hh_r : b_hh_f;

    const int g0 = lane;
    const int g1 = (lane < 16) ? (64 + lane) : 79;   // clamp keeps loads in-bounds

    // Weights in registers as float2 pairs (target v_pk_fma_f32).
    f2 wih0[5], wih1[5], whh0[10], whh1[10];
#pragma unroll
    for (int k = 0; k < 5; ++k) {
        wih0[k] = *(const f2*)(w_ih + g0 * II + 2 * k);
        wih1[k] = *(const f2*)(w_ih + g1 * II + 2 * k);
    }
#pragma unroll
    for (int k = 0; k < 10; ++k) {
        whh0[k] = *(const f2*)(w_hh + g0 * HH + 2 * k);
        whh1[k] = *(const f2*)(w_hh + g1 * HH + 2 * k);
    }
    const float bs0 = b_ih[g0] + b_hh[g0];
    const float bs1 = b_ih[g1] + b_hh[g1];

    // Unified activation: act = m * rcp(1 + exp(kn * v)) + a
    // sigmoid: kn=-1, m=1, a=0 ; tanh: kn=-2, m=2, a=-1
    const bool is_tanh0 = (g0 >= 40) && (g0 < 60);
    const float kn0 = is_tanh0 ? -2.0f : -1.0f;
    const float m0  = is_tanh0 ?  2.0f :  1.0f;
    const float a0  = is_tanh0 ? -1.0f :  0.0f;

    __shared__ f4 hlds[5];   // h[20] broadcast buffer (one sample per block)

    if (lane < HH) ((float*)hlds)[lane] = 0.0f;
    __builtin_amdgcn_wave_barrier();

    // Precomputed shuffle sources (meaningful for lanes < 20)
    const int jj    = (lane < HH) ? lane : 0;
    const int src_f = 20 + jj;
    const int src_g = 40 + jj;
    const int src_o = (jj < 4) ? (60 + jj) : (jj - 4); // o[0:4] in act0@lanes60..63, o[4:20] in act1@lanes0..15

    const int t0    = dir ? (TT - 1) : 0;
    const int xstep = dir ? -(BB * II) : (BB * II);
    const int ostep = dir ? -(BB * 2 * HH) : (BB * 2 * HH);

    int xoff = (t0 * BB + s) * II;
    int ooff = (t0 * BB + s) * (2 * HH) + dir * HH + jj;

    // Prime x double-buffer
    f2 xv[5];
#pragma unroll
    for (int k = 0; k < 5; ++k) xv[k] = *(const f2*)(x + xoff + 2 * k);

    float c = 0.0f, h = 0.0f;

    for (int tt = 0; tt < TT; ++tt) {
        // ---- prefetch next step's x (hides global latency under compute) ----
        const int xoffn = (tt < TT - 1) ? (xoff + xstep) : xoff;
        f2 xn[5];
#pragma unroll
        for (int k = 0; k < 5; ++k) xn[k] = *(const f2*)(x + xoffn + 2 * k);

        // ---- input projection (independent of h -> covers LDS latency) ----
        f2 acc2_0 = wih0[0] * xv[0];
        f2 acc2_1 = wih1[0] * xv[0];
#pragma unroll
        for (int k = 1; k < 5; ++k) {
            acc2_0 += wih0[k] * xv[k];
            acc2_1 += wih1[k] * xv[k];
        }

        // ---- recurrent projection: read h (broadcast, 5x ds_read_b128) ----
        f4 hb[5];
#pragma unroll
        for (int k = 0; k < 5; ++k) hb[k] = hlds[k];
#pragma unroll
        for (int k = 0; k < 5; ++k) {
            f2 lo; lo[0] = hb[k][0]; lo[1] = hb[k][1];
            f2 hi; hi[0] = hb[k][2]; hi[1] = hb[k][3];
            acc2_0 += whh0[2 * k] * lo;
            acc2_0 += whh0[2 * k + 1] * hi;
            acc2_1 += whh1[2 * k] * lo;
            acc2_1 += whh1[2 * k + 1] * hi;
        }
        const float v0 = bs0 + acc2_0[0] + acc2_0[1];
        const float v1 = bs1 + acc2_1[0] + acc2_1[1];

        // ---- activations (branch-free) ----
        const float e0   = __expf(kn0 * v0);
        const float act0 = __builtin_fmaf(m0, __builtin_amdgcn_rcpf(1.0f + e0), a0);
        const float e1   = __expf(-v1);
        const float act1 = __builtin_amdgcn_rcpf(1.0f + e1);

        // ---- gate exchange (3x ds_bpermute, indices precomputed) ----
        const float fj = __shfl(act0, src_f);
        const float gj = __shfl(act0, src_g);
        const float mg = (lane >= 60) ? act0 : act1;
        const float oj = __shfl(mg, src_o);

        // ---- state update on lanes 0..19 (lane == hidden unit j) ----
        if (lane < HH) {
            const float ij = act0;                     // g0 = lane in [0,20) = i-gate
            c = __builtin_fmaf(fj, c, ij * gj);
            const float ec = __expf(-2.0f * c);
            const float th = __builtin_fmaf(2.0f, __builtin_amdgcn_rcpf(1.0f + ec), -1.0f);
            h = oj * th;
            ((float*)hlds)[lane] = h;                  // wave-local, no barrier needed
            out[ooff] = h;
        }
        __builtin_amdgcn_wave_barrier();               // compiler fence only (free)

        xv[0] = xn[0]; xv[1] = xn[1]; xv[2] = xn[2]; xv[3] = xn[3]; xv[4] = xn[4];
        xoff = xoffn;
        ooff += ostep;
    }
}

extern "C" void kernel_launch(void* const* d_in, const int* in_sizes, int n_in,
                              void* d_out, int out_size, void* d_ws, size_t ws_size,
                              hipStream_t stream) {
    const float* xp     = (const float*)d_in[0];
    const float* w_ih_f = (const float*)d_in[1];
    const float* w_hh_f = (const float*)d_in[2];
    const float* b_ih_f = (const float*)d_in[3];
    const float* b_hh_f = (const float*)d_in[4];
    const float* w_ih_r = (const float*)d_in[5];
    const float* w_hh_r = (const float*)d_in[6];
    const float* b_ih_r = (const float*)d_in[7];
    const float* b_hh_r = (const float*)d_in[8];
    float* outp = (float*)d_out;

    hipLaunchKernelGGL(lstm_bidir, dim3(1024), dim3(64), 0, stream,
                       xp, w_ih_f, w_hh_f, b_ih_f, b_hh_f,
                       w_ih_r, w_hh_r, b_ih_r, b_hh_r, outp);
}

// Round 3
// 926.063 us; speedup vs baseline: 1.3373x; 1.3373x over previous
//
#include <hip/hip_runtime.h>

typedef float f2 __attribute__((ext_vector_type(2)));
typedef float f4 __attribute__((ext_vector_type(4)));

#define TT 2048
#define BB 512
#define II 10
#define HH 20

// One wave (64 lanes) per (direction, batch-sample) sequence.
// Lane j (j<20) computes ALL FOUR gates (i,f,g,o) for hidden unit j:
// rows j, 20+j, 40+j, 60+j of w_ih/w_hh. The c/h update is fully lane-local;
// the ONLY cross-lane operation per step is the 20-float h broadcast via LDS.
// Lanes 20..63 compute clamped-row garbage and never store.
__global__ __launch_bounds__(64) void lstm_bidir(
    const float* __restrict__ x,
    const float* __restrict__ w_ih_f, const float* __restrict__ w_hh_f,
    const float* __restrict__ b_ih_f, const float* __restrict__ b_hh_f,
    const float* __restrict__ w_ih_r, const float* __restrict__ w_hh_r,
    const float* __restrict__ b_ih_r, const float* __restrict__ b_hh_r,
    float* __restrict__ out)
{
    const int lane = threadIdx.x;
    const int blk  = blockIdx.x;
    const int dir  = blk >> 9;     // 0 = forward, 1 = reverse
    const int s    = blk & 511;    // batch sample

    const float* __restrict__ w_ih = dir ? w_ih_r : w_ih_f;
    const float* __restrict__ w_hh = dir ? w_hh_r : w_hh_f;
    const float* __restrict__ b_ih = dir ? b_ih_r : b_ih_f;
    const float* __restrict__ b_hh = dir ? b_hh_r : b_hh_f;

    const bool valid = (lane < HH);
    const int  j     = valid ? lane : (HH - 1);     // clamp keeps loads in-bounds

    // Gate rows for hidden unit j (PyTorch order i,f,g,o).
    // Weights in registers as float2 pairs (v_pk_fma_f32).
    f2 whh[4][10], wih[4][5];
    float bs[4];
#pragma unroll
    for (int g = 0; g < 4; ++g) {
        const int r = g * HH + j;
#pragma unroll
        for (int k = 0; k < 10; ++k) whh[g][k] = *(const f2*)(w_hh + r * HH + 2 * k);
#pragma unroll
        for (int k = 0; k < 5; ++k)  wih[g][k] = *(const f2*)(w_ih + r * II + 2 * k);
        bs[g] = b_ih[r] + b_hh[r];
    }

    __shared__ f4 hlds[5];   // h[20] broadcast buffer (one sample per block)
    if (valid) ((float*)hlds)[lane] = 0.0f;
    __builtin_amdgcn_wave_barrier();

    const int t0    = dir ? (TT - 1) : 0;
    const int xstep = dir ? -(BB * II) : (BB * II);
    const int ostep = dir ? -(BB * 2 * HH) : (BB * 2 * HH);

    int xoff  = (t0 * BB + s) * II;
    int xoffn = xoff + xstep;
    int ooff  = (t0 * BB + s) * (2 * HH) + dir * HH + j;

    // Prime x double-buffer (t0, t0+1)
    f2 xv[5], xn[5];
#pragma unroll
    for (int k = 0; k < 5; ++k) xv[k] = *(const f2*)(x + xoff  + 2 * k);
#pragma unroll
    for (int k = 0; k < 5; ++k) xn[k] = *(const f2*)(x + xoffn + 2 * k);

    // x-projection + bias for step t0 (off the recurrent critical path)
    float xproj[4];
#pragma unroll
    for (int g = 0; g < 4; ++g) {
        f2 p = wih[g][0] * xv[0];
#pragma unroll
        for (int k = 1; k < 5; ++k) p += wih[g][k] * xv[k];
        xproj[g] = bs[g] + p[0] + p[1];
    }

    // Prime the h broadcast (zeros)
    f4 hb[5];
#pragma unroll
    for (int k = 0; k < 5; ++k) hb[k] = hlds[k];

    float c = 0.0f, h = 0.0f;

#pragma unroll 2
    for (int tt = 0; tt < TT; ++tt) {
        // ---- recurrent dots: 4 gates x 10 pk-FMA, two accumulators each ----
        f2 a0[4], a1[4];
#pragma unroll
        for (int g = 0; g < 4; ++g) { a0[g] = f2{0.f, 0.f}; a1[g] = f2{0.f, 0.f}; }
#pragma unroll
        for (int k = 0; k < 5; ++k) {
            const f4 hv = hb[k];
            f2 lo; lo[0] = hv[0]; lo[1] = hv[1];
            f2 hi; hi[0] = hv[2]; hi[1] = hv[3];
#pragma unroll
            for (int g = 0; g < 4; ++g) {
                a0[g] += whh[g][2 * k]     * lo;
                a1[g] += whh[g][2 * k + 1] * hi;
            }
        }
        float v[4];
#pragma unroll
        for (int g = 0; g < 4; ++g) {
            const f2 a = a0[g] + a1[g];
            v[g] = xproj[g] + a[0] + a[1];
        }

        // ---- activations (all lane-local, 4 independent chains) ----
        const float ig = __builtin_amdgcn_rcpf(1.0f + __expf(-v[0]));                     // sigmoid i
        const float fg = __builtin_amdgcn_rcpf(1.0f + __expf(-v[1]));                     // sigmoid f
        const float gg = __builtin_fmaf(2.0f,
                          __builtin_amdgcn_rcpf(1.0f + __expf(-2.0f * v[2])), -1.0f);     // tanh g
        const float og = __builtin_amdgcn_rcpf(1.0f + __expf(-v[3]));                     // sigmoid o

        // ---- lane-local state update ----
        c = __builtin_fmaf(fg, c, ig * gg);
        const float th = __builtin_fmaf(2.0f,
                          __builtin_amdgcn_rcpf(1.0f + __expf(-2.0f * c)), -1.0f);        // tanh c
        h = og * th;

        if (valid) {
            ((float*)hlds)[lane] = h;    // wave-local write, no barrier needed
            out[ooff] = h;
        }
        __builtin_amdgcn_wave_barrier();

        // ---- broadcast read for next step ----
#pragma unroll
        for (int k = 0; k < 5; ++k) hb[k] = hlds[k];

        // ---- advance x pipeline while the LDS read is in flight ----
#pragma unroll
        for (int k = 0; k < 5; ++k) xv[k] = xn[k];
        xoff  = xoffn;
        xoffn = (tt < TT - 2) ? (xoff + xstep) : xoff;
#pragma unroll
        for (int k = 0; k < 5; ++k) xn[k] = *(const f2*)(x + xoffn + 2 * k);

        // x-projection for step tt+1 (independent of hb -> fills lgkm wait)
#pragma unroll
        for (int g = 0; g < 4; ++g) {
            f2 p = wih[g][0] * xv[0];
#pragma unroll
            for (int k = 1; k < 5; ++k) p += wih[g][k] * xv[k];
            xproj[g] = bs[g] + p[0] + p[1];
        }

        ooff += ostep;
    }
}

extern "C" void kernel_launch(void* const* d_in, const int* in_sizes, int n_in,
                              void* d_out, int out_size, void* d_ws, size_t ws_size,
                              hipStream_t stream) {
    const float* xp     = (const float*)d_in[0];
    const float* w_ih_f = (const float*)d_in[1];
    const float* w_hh_f = (const float*)d_in[2];
    const float* b_ih_f = (const float*)d_in[3];
    const float* b_hh_f = (const float*)d_in[4];
    const float* w_ih_r = (const float*)d_in[5];
    const float* w_hh_r = (const float*)d_in[6];
    const float* b_ih_r = (const float*)d_in[7];
    const float* b_hh_r = (const float*)d_in[8];
    float* outp = (float*)d_out;

    hipLaunchKernelGGL(lstm_bidir, dim3(1024), dim3(64), 0, stream,
                       xp, w_ih_f, w_hh_f, b_ih_f, b_hh_f,
                       w_ih_r, w_hh_r, b_ih_r, b_hh_r, outp);
}